// Round 2
// baseline (3893.610 us; speedup 1.0000x reference)
//
#include <hip/hip_runtime.h>
#include <hip/hip_cooperative_groups.h>
#include <hip/hip_bf16.h>
#include <math.h>

namespace cg = cooperative_groups;

#define B_ 8
#define T_ 12
#define N_ 200
#define H_ 64
#define D_ 32
#define R_ 1600   // B*N rows

__device__ __forceinline__ float sigm(float v) { return 1.f / (1.f + expf(-v)); }

// ======== Phase A: full dy-GRU chain over all t + P/Q projections ========
// One block (64 thr = 1 wave) per row (b,n). Row-local across time.
__global__ void __launch_bounds__(64) k_dyall(
        const float* __restrict__ x,  const float* __restrict__ nf,
        const float* __restrict__ Ws2d, const float* __restrict__ bs2d,
        const float* __restrict__ Wrz,  const float* __restrict__ brz,
        const float* __restrict__ Wh,   const float* __restrict__ bh,
        const float* __restrict__ Wc2,  const float* __restrict__ Wm2,
        float* __restrict__ Pc, float* __restrict__ Qc,
        float* __restrict__ Pm, float* __restrict__ Qm) {
    __shared__ float dy[32], in1[33], rz[64], in2[33], s_sh[32], nfs[64];
    int row = blockIdx.x; int b = row / N_, n = row % N_;
    int o = threadIdx.x;
    nfs[o] = nf[n * 64 + o];
    __syncthreads();
    if (o < 32) {
        float acc = bs2d[o];
        #pragma unroll 8
        for (int i = 0; i < 64; ++i) acc += nfs[i] * Ws2d[i * 32 + o];
        dy[o] = acc;
    }
    __syncthreads();
    for (int t = 0; t < T_; ++t) {
        if (o == 0) { float v = x[((b * T_ + t) * N_ + n) * 2]; in1[0] = v; in2[0] = v; }
        if (o < 32) in1[o + 1] = dy[o];
        __syncthreads();
        float acc = brz[o];
        #pragma unroll
        for (int i = 0; i < 33; ++i) acc += in1[i] * Wrz[i * 64 + o];
        rz[o] = sigm(acc);
        __syncthreads();
        if (o < 32) in2[o + 1] = rz[o] * dy[o];
        __syncthreads();
        if (o < 32) {
            float h = bh[o];
            #pragma unroll
            for (int i = 0; i < 33; ++i) h += in2[i] * Wh[i * 32 + o];
            h = tanhf(h);
            float z = rz[32 + o];
            float nd = z * dy[o] + (1.f - z) * h;
            dy[o] = nd;
            s_sh[o] = nd > 0.f ? nd : 0.f;
        }
        __syncthreads();
        size_t base = ((size_t)t * R_ + row) * 32;
        for (int idx = o; idx < 128; idx += 64) {
            int mat = idx >> 5, k = idx & 31;
            const float* W = (mat < 2) ? Wc2 : Wm2;
            int rb = (mat & 1) ? 32 : 0;   // Q uses W2 rows 32..63 (s_j half)
            float a = 0.f;
            #pragma unroll
            for (int i = 0; i < 32; ++i) a += s_sh[i] * W[(rb + i) * 32 + k];
            ((mat == 0) ? Pc : (mat == 1) ? Qc : (mat == 2) ? Pm : Qm)[base + k] = a;
        }
        __syncthreads();
    }
}

// ======== Phase B: all adjacency matrices A(t) in parallel ========
__global__ void __launch_bounds__(256) k_pairall(
        const float* __restrict__ Pc, const float* __restrict__ Qc,
        const float* __restrict__ Pm, const float* __restrict__ Qm,
        const float* __restrict__ bc2, const float* __restrict__ Wc1,
        const float* __restrict__ bc1,
        const float* __restrict__ bm2, const float* __restrict__ Wm1,
        const float* __restrict__ bm1,
        float* __restrict__ out) {
    __shared__ float sPc[16][33], sQc[16][33], sPm[16][33], sQm[16][33];
    __shared__ float sbc2[32], sWc1[32], sbm2[32], sWm1[32];
    int z = blockIdx.z;            // t*8 + b
    int t = z >> 3, b = z & 7;
    int i0 = blockIdx.x * 16, j0 = blockIdx.y * 16;
    int tid = threadIdx.y * 16 + threadIdx.x;
    size_t tb = (size_t)t * R_ + b * N_;
    for (int l = tid; l < 512; l += 256) {
        int r = l >> 5, k = l & 31;
        int gi = i0 + r, gj = j0 + r;
        sPc[r][k] = (gi < N_) ? Pc[(tb + gi) * 32 + k] : 0.f;
        sPm[r][k] = (gi < N_) ? Pm[(tb + gi) * 32 + k] : 0.f;
        sQc[r][k] = (gj < N_) ? Qc[(tb + gj) * 32 + k] : 0.f;
        sQm[r][k] = (gj < N_) ? Qm[(tb + gj) * 32 + k] : 0.f;
    }
    if (tid < 32) { sbc2[tid] = bc2[tid]; sWc1[tid] = Wc1[tid];
                    sbm2[tid] = bm2[tid]; sWm1[tid] = Wm1[tid]; }
    __syncthreads();
    int i = i0 + threadIdx.y, j = j0 + threadIdx.x;
    if (i >= N_ || j >= N_) return;
    float g = 0.f, m = 0.f;
    #pragma unroll
    for (int k = 0; k < 32; ++k) {
        float hc = sPc[threadIdx.y][k] + sQc[threadIdx.x][k] + sbc2[k];
        g += (hc > 0.f ? hc : 0.f) * sWc1[k];
        float hm = sPm[threadIdx.y][k] + sQm[threadIdx.x][k] + sbm2[k];
        m += (hm > 0.f ? hm : 0.f) * sWm1[k];
    }
    g += bc1[0];
    m += bm1[0];
    // dy_graphs live right after pred (1600 floats) in d_out
    out[R_ + (((size_t)z * N_ + i) * N_ + j)] = g * sigm(m);
}

// ======== Phase C: the sequential 48-phase recurrence, one coop kernel ====
// grid = 400 blocks x 256 thr; wave w of block bk owns row bk*4+w (exactly 1600).
__global__ void __launch_bounds__(256) k_coop(
        const float* __restrict__ x,
        const float* __restrict__ Wru, const float* __restrict__ bru,
        const float* __restrict__ Wcd, const float* __restrict__ bcd,
        const float* __restrict__ Wp1, const float* __restrict__ bp1,
        const float* __restrict__ Wp2, const float* __restrict__ bp2,
        float* __restrict__ state, float* __restrict__ x1,
        float* __restrict__ rs, float* __restrict__ ub,
        float* __restrict__ out) {
    cg::grid_group grid = cg::this_grid();
    __shared__ float arow4[4][200];
    __shared__ float f4[4][200];      // 198 used
    const float* Aall = out + R_;
    int bk = blockIdx.x;
    int tid = threadIdx.x;
    int w = tid >> 6, lane = tid & 63;
    int row = bk * 4 + w;
    int b = row / N_, i = row % N_;

    state[row * 64 + lane] = 0.f;     // state0 = 0
    grid.sync();

    for (int t = 0; t < T_; ++t) {
        const float* At = Aall + (((size_t)(t * 8 + b) * N_ + i) * N_);
        for (int j = lane; j < N_; j += 64) arow4[w][j] = At[j];
        __syncthreads();
        // ---- P1: x1 = A @ [xt | state] ----
        for (int cc = lane; cc < 66; cc += 64) {
            float acc = 0.f;
            if (cc < 2) {
                for (int j = 0; j < N_; ++j) acc += arow4[w][j] * x[((b * T_ + t) * N_ + j) * 2 + cc];
            } else {
                int c = cc - 2;
                #pragma unroll 4
                for (int j = 0; j < N_; ++j) acc += arow4[w][j] * state[(b * N_ + j) * 64 + c];
            }
            x1[row * 66 + cc] = acc;
        }
        grid.sync();
        // ---- P2: x2 (local), f=[xt,state,x1,x2], ru -> rs,u ----
        if (lane < 2) f4[w][lane] = x[((b * T_ + t) * N_ + i) * 2 + lane];
        f4[w][2 + lane] = state[row * 64 + lane];
        for (int cc = lane; cc < 66; cc += 64) f4[w][66 + cc] = x1[row * 66 + cc];
        for (int cc = lane; cc < 66; cc += 64) {
            float acc = 0.f;
            #pragma unroll 4
            for (int j = 0; j < N_; ++j) acc += arow4[w][j] * x1[(b * N_ + j) * 66 + cc];
            f4[w][132 + cc] = acc;
        }
        __syncthreads();
        {
            int c = tid & 127, h2 = tid >> 7;       // h2 selects row pair
            int ra = h2 * 2;
            float a0 = bru[c], a1 = bru[c];
            #pragma unroll 2
            for (int k = 0; k < 198; ++k) {
                float wv = Wru[k * 128 + c];
                a0 += f4[ra][k] * wv;
                a1 += f4[ra + 1][k] * wv;
            }
            int r0 = bk * 4 + ra;
            float v0 = sigm(a0), v1 = sigm(a1);
            if (c < 64) {
                rs[r0 * 64 + c]       = v0 * f4[ra][2 + c];
                rs[(r0 + 1) * 64 + c] = v1 * f4[ra + 1][2 + c];
            } else {
                ub[r0 * 64 + c - 64]       = v0;
                ub[(r0 + 1) * 64 + c - 64] = v1;
            }
        }
        grid.sync();
        // ---- P3: x1c = A @ [xt | rs] (arow4 still resident) ----
        for (int cc = lane; cc < 66; cc += 64) {
            float acc = 0.f;
            if (cc < 2) {
                for (int j = 0; j < N_; ++j) acc += arow4[w][j] * x[((b * T_ + t) * N_ + j) * 2 + cc];
            } else {
                int c = cc - 2;
                #pragma unroll 4
                for (int j = 0; j < N_; ++j) acc += arow4[w][j] * rs[(b * N_ + j) * 64 + c];
            }
            x1[row * 66 + cc] = acc;
        }
        grid.sync();
        // ---- P4: x2c (local), fc=[xt,rs,x1c,x2c], cand, state update ----
        if (lane < 2) f4[w][lane] = x[((b * T_ + t) * N_ + i) * 2 + lane];
        f4[w][2 + lane] = rs[row * 64 + lane];
        for (int cc = lane; cc < 66; cc += 64) f4[w][66 + cc] = x1[row * 66 + cc];
        for (int cc = lane; cc < 66; cc += 64) {
            float acc = 0.f;
            #pragma unroll 4
            for (int j = 0; j < N_; ++j) acc += arow4[w][j] * x1[(b * N_ + j) * 66 + cc];
            f4[w][132 + cc] = acc;
        }
        __syncthreads();
        {
            int r = tid >> 6, c = tid & 63;         // 4 rows x 64 cols = 256
            float a = bcd[c];
            #pragma unroll 2
            for (int k = 0; k < 198; ++k) a += f4[r][k] * Wcd[k * 64 + c];
            float cnd = tanhf(a);
            int rr_ = bk * 4 + r;
            float u = ub[rr_ * 64 + c];
            float st = state[rr_ * 64 + c];
            state[rr_ * 64 + c] = u * st + (1.f - u) * cnd;
        }
        grid.sync();
    }
    // ---- pred head: wave per row ----
    {
        f4[w][lane] = state[row * 64 + lane];
        __syncthreads();
        float acc = bp1[lane];
        #pragma unroll 8
        for (int a = 0; a < 64; ++a) acc += f4[w][a] * Wp1[a * 64 + lane];
        acc = acc > 0.f ? acc : 0.01f * acc;        // leaky_relu slope 0.01
        float v = acc * Wp2[lane];
        #pragma unroll
        for (int off = 32; off > 0; off >>= 1) v += __shfl_down(v, off);
        if (lane == 0) out[row] = v + bp2[0];
    }
}

extern "C" void kernel_launch(void* const* d_in, const int* in_sizes, int n_in,
                              void* d_out, int out_size, void* d_ws, size_t ws_size,
                              hipStream_t stream) {
    const float* x    = (const float*)d_in[0];
    const float* nf   = (const float*)d_in[1];
    const float* Ws2d = (const float*)d_in[2];
    const float* bs2d = (const float*)d_in[3];
    const float* Wrz  = (const float*)d_in[4];
    const float* brz  = (const float*)d_in[5];
    const float* Wh   = (const float*)d_in[6];
    const float* bh   = (const float*)d_in[7];
    const float* Wc2  = (const float*)d_in[8];
    const float* bc2  = (const float*)d_in[9];
    const float* Wc1  = (const float*)d_in[10];
    const float* bc1  = (const float*)d_in[11];
    const float* Wm2  = (const float*)d_in[12];
    const float* bm2  = (const float*)d_in[13];
    const float* Wm1  = (const float*)d_in[14];
    const float* bm1  = (const float*)d_in[15];
    const float* Wru  = (const float*)d_in[16];
    const float* bru  = (const float*)d_in[17];
    const float* Wcand= (const float*)d_in[18];
    const float* bcand= (const float*)d_in[19];
    const float* Wp1  = (const float*)d_in[20];
    const float* bp1  = (const float*)d_in[21];
    const float* Wp2  = (const float*)d_in[22];
    const float* bp2  = (const float*)d_in[23];
    float* out = (float*)d_out;

    float* ws = (float*)d_ws;
    float* Pc = ws;                          // 12*1600*32
    float* Qc = Pc + (size_t)T_ * R_ * 32;
    float* Pm = Qc + (size_t)T_ * R_ * 32;
    float* Qm = Pm + (size_t)T_ * R_ * 32;
    float* state = Qm + (size_t)T_ * R_ * 32; // 1600*64
    float* x1    = state + R_ * 64;           // 1600*66
    float* rs    = x1 + R_ * 66;              // 1600*64
    float* ub    = rs + R_ * 64;              // 1600*64
    // total ~11.5 MB

    k_dyall<<<R_, 64, 0, stream>>>(x, nf, Ws2d, bs2d, Wrz, brz, Wh, bh,
                                   Wc2, Wm2, Pc, Qc, Pm, Qm);
    k_pairall<<<dim3(13, 13, 96), dim3(16, 16), 0, stream>>>(
        Pc, Qc, Pm, Qm, bc2, Wc1, bc1, bm2, Wm1, bm1, out);

    void* args[] = { (void*)&x, (void*)&Wru, (void*)&bru, (void*)&Wcand, (void*)&bcand,
                     (void*)&Wp1, (void*)&bp1, (void*)&Wp2, (void*)&bp2,
                     (void*)&state, (void*)&x1, (void*)&rs, (void*)&ub, (void*)&out };
    hipLaunchCooperativeKernel((const void*)k_coop, dim3(400), dim3(256),
                               args, 0, stream);
}

// Round 3
// 2060.334 us; speedup vs baseline: 1.8898x; 1.8898x over previous
//
#include <hip/hip_runtime.h>
#include <math.h>

#define B_ 8
#define T_ 12
#define N_ 200
#define R_ 1600   // B*N
#define F_ 66     // spmm output cols  [xt(2) | S(64)]
#define G_ 198    // gate input cols   [xt | S | x1 | x2]

__device__ __forceinline__ float sigm(float v) { return 1.f / (1.f + expf(-v)); }

// ======== Phase A: full dy-GRU chain over all t + P/Q projections ========
// One wave per row (b,n); also zero-inits state.
__global__ void __launch_bounds__(64) k_dyall(
        const float* __restrict__ x,  const float* __restrict__ nf,
        const float* __restrict__ Ws2d, const float* __restrict__ bs2d,
        const float* __restrict__ Wrz,  const float* __restrict__ brz,
        const float* __restrict__ Wh,   const float* __restrict__ bh,
        const float* __restrict__ Wc2,  const float* __restrict__ Wm2,
        float* __restrict__ Pc, float* __restrict__ Qc,
        float* __restrict__ Pm, float* __restrict__ Qm,
        float* __restrict__ state) {
    __shared__ float dy[32], in1[33], rz[64], in2[33], s_sh[32], nfs[64];
    int row = blockIdx.x; int b = row / N_, n = row % N_;
    int o = threadIdx.x;
    state[row * 64 + o] = 0.f;                 // state0 = 0
    nfs[o] = nf[n * 64 + o];
    __syncthreads();
    if (o < 32) {
        float acc = bs2d[o];
        #pragma unroll 8
        for (int i = 0; i < 64; ++i) acc += nfs[i] * Ws2d[i * 32 + o];
        dy[o] = acc;
    }
    __syncthreads();
    for (int t = 0; t < T_; ++t) {
        if (o == 0) { float v = x[((b * T_ + t) * N_ + n) * 2]; in1[0] = v; in2[0] = v; }
        if (o < 32) in1[o + 1] = dy[o];
        __syncthreads();
        float acc = brz[o];
        #pragma unroll
        for (int i = 0; i < 33; ++i) acc += in1[i] * Wrz[i * 64 + o];
        rz[o] = sigm(acc);
        __syncthreads();
        if (o < 32) in2[o + 1] = rz[o] * dy[o];
        __syncthreads();
        if (o < 32) {
            float h = bh[o];
            #pragma unroll
            for (int i = 0; i < 33; ++i) h += in2[i] * Wh[i * 32 + o];
            h = tanhf(h);
            float z = rz[32 + o];
            float nd = z * dy[o] + (1.f - z) * h;
            dy[o] = nd;
            s_sh[o] = nd > 0.f ? nd : 0.f;
        }
        __syncthreads();
        size_t base = ((size_t)t * R_ + row) * 32;
        for (int idx = o; idx < 128; idx += 64) {
            int mat = idx >> 5, k = idx & 31;
            const float* W = (mat < 2) ? Wc2 : Wm2;
            int rb = (mat & 1) ? 32 : 0;
            float a = 0.f;
            #pragma unroll
            for (int i = 0; i < 32; ++i) a += s_sh[i] * W[(rb + i) * 32 + k];
            ((mat == 0) ? Pc : (mat == 1) ? Qc : (mat == 2) ? Pm : Qm)[base + k] = a;
        }
        __syncthreads();
    }
}

// ======== Phase B: all 96 adjacency matrices in parallel ========
__global__ void __launch_bounds__(256) k_pairall(
        const float* __restrict__ Pc, const float* __restrict__ Qc,
        const float* __restrict__ Pm, const float* __restrict__ Qm,
        const float* __restrict__ bc2, const float* __restrict__ Wc1,
        const float* __restrict__ bc1,
        const float* __restrict__ bm2, const float* __restrict__ Wm1,
        const float* __restrict__ bm1,
        float* __restrict__ out) {
    __shared__ float sPc[16][33], sQc[16][33], sPm[16][33], sQm[16][33];
    __shared__ float sbc2[32], sWc1[32], sbm2[32], sWm1[32];
    int z = blockIdx.z;            // t*8 + b
    int t = z >> 3, b = z & 7;
    int i0 = blockIdx.x * 16, j0 = blockIdx.y * 16;
    int tid = threadIdx.y * 16 + threadIdx.x;
    size_t tb = (size_t)t * R_ + b * N_;
    for (int l = tid; l < 512; l += 256) {
        int r = l >> 5, k = l & 31;
        int gi = i0 + r, gj = j0 + r;
        sPc[r][k] = (gi < N_) ? Pc[(tb + gi) * 32 + k] : 0.f;
        sPm[r][k] = (gi < N_) ? Pm[(tb + gi) * 32 + k] : 0.f;
        sQc[r][k] = (gj < N_) ? Qc[(tb + gj) * 32 + k] : 0.f;
        sQm[r][k] = (gj < N_) ? Qm[(tb + gj) * 32 + k] : 0.f;
    }
    if (tid < 32) { sbc2[tid] = bc2[tid]; sWc1[tid] = Wc1[tid];
                    sbm2[tid] = bm2[tid]; sWm1[tid] = Wm1[tid]; }
    __syncthreads();
    int i = i0 + threadIdx.y, j = j0 + threadIdx.x;
    if (i >= N_ || j >= N_) return;
    float g = 0.f, m = 0.f;
    #pragma unroll
    for (int k = 0; k < 32; ++k) {
        float hc = sPc[threadIdx.y][k] + sQc[threadIdx.x][k] + sbc2[k];
        g += (hc > 0.f ? hc : 0.f) * sWc1[k];
        float hm = sPm[threadIdx.y][k] + sQm[threadIdx.x][k] + sbm2[k];
        m += (hm > 0.f ? hm : 0.f) * sWm1[k];
    }
    g += bc1[0];
    m += bm1[0];
    out[R_ + (((size_t)z * N_ + i) * N_ + j)] = g * sigm(m);
}

// ======== hop1 spmm: x1[b,i,:] = A[b,i,:] @ [xt | S], 8 rows/block ========
__global__ void __launch_bounds__(256) k_spmm1(
        const float* __restrict__ A, const float* __restrict__ x, int t,
        const float* __restrict__ S, float* __restrict__ x1) {
    __shared__ float a8[8 * N_];
    __shared__ float xch[64 * F_];
    int bx = blockIdx.x;
    int b = bx / 25, i0 = (bx % 25) * 8;
    int tid = threadIdx.x;
    const float* Ab = A + ((size_t)b * N_ + i0) * N_;
    for (int idx = tid; idx < 8 * N_; idx += 256) a8[idx] = Ab[idx];
    int r = tid >> 5, cg = tid & 31;
    float acc0 = 0.f, acc1 = 0.f, acc2 = 0.f;
    const float* xt = x + ((size_t)(b * T_ + t)) * N_ * 2;
    for (int j0 = 0; j0 < N_; j0 += 64) {
        int jc = min(64, N_ - j0);
        __syncthreads();
        for (int idx = tid; idx < jc * F_; idx += 256) {
            int jj = idx / F_, c = idx - jj * F_;
            xch[idx] = (c < 2) ? xt[(j0 + jj) * 2 + c]
                               : S[((size_t)b * N_ + j0 + jj) * 64 + (c - 2)];
        }
        __syncthreads();
        const float* ar = a8 + r * N_ + j0;
        for (int jj = 0; jj < jc; ++jj) {
            float av = ar[jj];
            const float* xr = xch + jj * F_;
            acc0 += av * xr[cg];
            acc1 += av * xr[cg + 32];
            if (cg < 2) acc2 += av * xr[cg + 64];
        }
    }
    size_t orow = ((size_t)b * N_ + i0 + r) * F_;
    x1[orow + cg] = acc0;
    x1[orow + cg + 32] = acc1;
    if (cg < 2) x1[orow + cg + 64] = acc2;
}

// ======== fused hop2 + ru gate: 8 rows/block ========
__global__ void __launch_bounds__(256) k_ru8(
        const float* __restrict__ A, const float* __restrict__ x, int t,
        const float* __restrict__ state, const float* __restrict__ x1,
        const float* __restrict__ Wru, const float* __restrict__ bru,
        float* __restrict__ rs, float* __restrict__ ub) {
    __shared__ float a8[8 * N_];
    __shared__ float xch[64 * F_];
    __shared__ float f8[8 * 200];
    int bx = blockIdx.x;
    int b = bx / 25, i0 = (bx % 25) * 8;
    int tid = threadIdx.x;
    const float* Ab = A + ((size_t)b * N_ + i0) * N_;
    for (int idx = tid; idx < 8 * N_; idx += 256) a8[idx] = Ab[idx];
    int r = tid >> 5, cg = tid & 31;
    float acc0 = 0.f, acc1 = 0.f, acc2 = 0.f;
    const float* x1b = x1 + (size_t)b * N_ * F_;
    for (int j0 = 0; j0 < N_; j0 += 64) {
        int jc = min(64, N_ - j0);
        __syncthreads();
        for (int idx = tid; idx < jc * F_; idx += 256) xch[idx] = x1b[j0 * F_ + idx];
        __syncthreads();
        const float* ar = a8 + r * N_ + j0;
        for (int jj = 0; jj < jc; ++jj) {
            float av = ar[jj];
            const float* xr = xch + jj * F_;
            acc0 += av * xr[cg];
            acc1 += av * xr[cg + 32];
            if (cg < 2) acc2 += av * xr[cg + 64];
        }
    }
    // assemble f = [xt | state | x1 | x2]
    f8[r * 200 + 132 + cg] = acc0;
    f8[r * 200 + 132 + cg + 32] = acc1;
    if (cg < 2) f8[r * 200 + 132 + cg + 64] = acc2;
    const float* xt = x + ((size_t)(b * T_ + t)) * N_ * 2;
    if (tid < 16) { int rr = tid >> 1, c = tid & 1; f8[rr * 200 + c] = xt[(i0 + rr) * 2 + c]; }
    for (int idx = tid; idx < 8 * 64; idx += 256) {
        int rr = idx >> 6, c = idx & 63;
        f8[rr * 200 + 2 + c] = state[((size_t)b * N_ + i0 + rr) * 64 + c];
    }
    for (int idx = tid; idx < 8 * F_; idx += 256) {
        int rr = idx / F_, c = idx - rr * F_;
        f8[rr * 200 + 66 + c] = x1b[(i0 + rr) * F_ + c];
    }
    __syncthreads();
    // gate matmul: 8 rows x 128 cols; thread: c=tid&127, rq=tid>>7 -> 4 rows
    int c = tid & 127, rq = tid >> 7;
    float g0 = bru[c], g1 = g0, g2 = g0, g3 = g0;
    const float* fb = f8 + rq * 4 * 200;
    #pragma unroll 2
    for (int k = 0; k < G_; ++k) {
        float wv = Wru[k * 128 + c];
        g0 += fb[k] * wv; g1 += fb[200 + k] * wv;
        g2 += fb[400 + k] * wv; g3 += fb[600 + k] * wv;
    }
    float v0 = sigm(g0), v1 = sigm(g1), v2 = sigm(g2), v3 = sigm(g3);
    float vv[4] = { v0, v1, v2, v3 };
    #pragma unroll
    for (int m = 0; m < 4; ++m) {
        int rl = rq * 4 + m;
        size_t grow = (size_t)b * N_ + i0 + rl;
        if (c < 64) rs[grow * 64 + c] = vv[m] * f8[rl * 200 + 2 + c];
        else        ub[grow * 64 + (c - 64)] = vv[m];
    }
}

// ======== fused hop2 + cand gate + state update: 8 rows/block ========
__global__ void __launch_bounds__(256) k_cand8(
        const float* __restrict__ A, const float* __restrict__ x, int t,
        const float* __restrict__ rsin, const float* __restrict__ x1,
        const float* __restrict__ Wcd, const float* __restrict__ bcd,
        const float* __restrict__ ub, float* __restrict__ state) {
    __shared__ float a8[8 * N_];
    __shared__ float xch[64 * F_];
    __shared__ float f8[8 * 200];
    int bx = blockIdx.x;
    int b = bx / 25, i0 = (bx % 25) * 8;
    int tid = threadIdx.x;
    const float* Ab = A + ((size_t)b * N_ + i0) * N_;
    for (int idx = tid; idx < 8 * N_; idx += 256) a8[idx] = Ab[idx];
    int r = tid >> 5, cg = tid & 31;
    float acc0 = 0.f, acc1 = 0.f, acc2 = 0.f;
    const float* x1b = x1 + (size_t)b * N_ * F_;
    for (int j0 = 0; j0 < N_; j0 += 64) {
        int jc = min(64, N_ - j0);
        __syncthreads();
        for (int idx = tid; idx < jc * F_; idx += 256) xch[idx] = x1b[j0 * F_ + idx];
        __syncthreads();
        const float* ar = a8 + r * N_ + j0;
        for (int jj = 0; jj < jc; ++jj) {
            float av = ar[jj];
            const float* xr = xch + jj * F_;
            acc0 += av * xr[cg];
            acc1 += av * xr[cg + 32];
            if (cg < 2) acc2 += av * xr[cg + 64];
        }
    }
    f8[r * 200 + 132 + cg] = acc0;
    f8[r * 200 + 132 + cg + 32] = acc1;
    if (cg < 2) f8[r * 200 + 132 + cg + 64] = acc2;
    const float* xt = x + ((size_t)(b * T_ + t)) * N_ * 2;
    if (tid < 16) { int rr = tid >> 1, c = tid & 1; f8[rr * 200 + c] = xt[(i0 + rr) * 2 + c]; }
    for (int idx = tid; idx < 8 * 64; idx += 256) {
        int rr = idx >> 6, c = idx & 63;
        f8[rr * 200 + 2 + c] = rsin[((size_t)b * N_ + i0 + rr) * 64 + c];
    }
    for (int idx = tid; idx < 8 * F_; idx += 256) {
        int rr = idx / F_, c = idx - rr * F_;
        f8[rr * 200 + 66 + c] = x1b[(i0 + rr) * F_ + c];
    }
    __syncthreads();
    // cand matmul: 8 rows x 64 cols; thread: c=tid&63, rq=tid>>6 -> 2 rows
    int c = tid & 63, rq = tid >> 6;
    float g0 = bcd[c], g1 = g0;
    const float* fb = f8 + rq * 2 * 200;
    #pragma unroll 2
    for (int k = 0; k < G_; ++k) {
        float wv = Wcd[k * 64 + c];
        g0 += fb[k] * wv; g1 += fb[200 + k] * wv;
    }
    #pragma unroll
    for (int m = 0; m < 2; ++m) {
        int rl = rq * 2 + m;
        size_t grow = (size_t)b * N_ + i0 + rl;
        float cnd = tanhf(m == 0 ? g0 : g1);
        float u = ub[grow * 64 + c];
        float st = state[grow * 64 + c];
        state[grow * 64 + c] = u * st + (1.f - u) * cnd;
    }
}

// ======== pred head ========
__global__ void __launch_bounds__(64) k_pred(
        const float* __restrict__ state,
        const float* __restrict__ Wp1, const float* __restrict__ bp1,
        const float* __restrict__ Wp2, const float* __restrict__ bp2,
        float* __restrict__ out) {
    __shared__ float st[64];
    int row = blockIdx.x;
    int tid = threadIdx.x;
    st[tid] = state[row * 64 + tid];
    __syncthreads();
    float acc = bp1[tid];
    #pragma unroll 8
    for (int a = 0; a < 64; ++a) acc += st[a] * Wp1[a * 64 + tid];
    acc = acc > 0.f ? acc : 0.01f * acc;
    float v = acc * Wp2[tid];
    #pragma unroll
    for (int off = 32; off > 0; off >>= 1) v += __shfl_down(v, off);
    if (tid == 0) out[row] = v + bp2[0];
}

extern "C" void kernel_launch(void* const* d_in, const int* in_sizes, int n_in,
                              void* d_out, int out_size, void* d_ws, size_t ws_size,
                              hipStream_t stream) {
    const float* x    = (const float*)d_in[0];
    const float* nf   = (const float*)d_in[1];
    const float* Ws2d = (const float*)d_in[2];
    const float* bs2d = (const float*)d_in[3];
    const float* Wrz  = (const float*)d_in[4];
    const float* brz  = (const float*)d_in[5];
    const float* Wh   = (const float*)d_in[6];
    const float* bh   = (const float*)d_in[7];
    const float* Wc2  = (const float*)d_in[8];
    const float* bc2  = (const float*)d_in[9];
    const float* Wc1  = (const float*)d_in[10];
    const float* bc1  = (const float*)d_in[11];
    const float* Wm2  = (const float*)d_in[12];
    const float* bm2  = (const float*)d_in[13];
    const float* Wm1  = (const float*)d_in[14];
    const float* bm1  = (const float*)d_in[15];
    const float* Wru  = (const float*)d_in[16];
    const float* bru  = (const float*)d_in[17];
    const float* Wcand= (const float*)d_in[18];
    const float* bcand= (const float*)d_in[19];
    const float* Wp1  = (const float*)d_in[20];
    const float* bp1  = (const float*)d_in[21];
    const float* Wp2  = (const float*)d_in[22];
    const float* bp2  = (const float*)d_in[23];
    float* out = (float*)d_out;

    float* ws = (float*)d_ws;
    float* Pc = ws;                               // 12*1600*32 each
    float* Qc = Pc + (size_t)T_ * R_ * 32;
    float* Pm = Qc + (size_t)T_ * R_ * 32;
    float* Qm = Pm + (size_t)T_ * R_ * 32;
    float* state = Qm + (size_t)T_ * R_ * 32;     // 1600*64
    float* x1    = state + R_ * 64;               // 1600*66
    float* rs    = x1 + R_ * F_;                  // 1600*64
    float* ub    = rs + R_ * 64;                  // 1600*64

    k_dyall<<<R_, 64, 0, stream>>>(x, nf, Ws2d, bs2d, Wrz, brz, Wh, bh,
                                   Wc2, Wm2, Pc, Qc, Pm, Qm, state);
    k_pairall<<<dim3(13, 13, 96), dim3(16, 16), 0, stream>>>(
        Pc, Qc, Pm, Qm, bc2, Wc1, bc1, bm2, Wm1, bm1, out);

    for (int t = 0; t < T_; ++t) {
        const float* At = out + R_ + (size_t)t * B_ * N_ * N_;
        k_spmm1<<<200, 256, 0, stream>>>(At, x, t, state, x1);
        k_ru8  <<<200, 256, 0, stream>>>(At, x, t, state, x1, Wru, bru, rs, ub);
        k_spmm1<<<200, 256, 0, stream>>>(At, x, t, rs, x1);
        k_cand8<<<200, 256, 0, stream>>>(At, x, t, rs, x1, Wcand, bcand, ub, state);
    }

    k_pred<<<R_, 64, 0, stream>>>(state, Wp1, bp1, Wp2, bp2, out);
}